// Round 1
// baseline (341.837 us; speedup 1.0000x reference)
//
#include <hip/hip_runtime.h>

#define PI_D 3.141592653589793238462643383279502884

// ---------------------------------------------------------------------------
// Kernel 1: build the 32x64 combined operator C = B[:, :26] @ A[:26, :]
//   A = M64^3 (orthonormal DCT-II matrix applied 3x along H by the reference)
//   B = (M32^T)^3
// Single block, 256 threads, double accumulation, fp32 intermediates (matches
// the reference's fp32 matmul chain to ~1e-6).
// ---------------------------------------------------------------------------
__global__ __launch_bounds__(256) void build_C_kernel(float* __restrict__ Cout) {
    __shared__ float sM[64 * 64];    // M64
    __shared__ float sQ[64 * 64];    // M64^2
    __shared__ float sA[64 * 64];    // M64^3
    __shared__ float s32a[32 * 32];  // M32
    __shared__ float s32b[32 * 32];  // M32^2
    __shared__ float s32c[32 * 32];  // M32^3
    const int t = threadIdx.x;

    for (int i = t; i < 4096; i += 256) {
        int k = i >> 6, n = i & 63;
        double v = (k == 0) ? (1.0 / sqrt(64.0))
                            : sqrt(2.0 / 64.0) * cos(PI_D * (2.0 * n + 1.0) * (double)k / 128.0);
        sM[i] = (float)v;
    }
    for (int i = t; i < 1024; i += 256) {
        int k = i >> 5, n = i & 31;
        double v = (k == 0) ? (1.0 / sqrt(32.0))
                            : sqrt(2.0 / 32.0) * cos(PI_D * (2.0 * n + 1.0) * (double)k / 64.0);
        s32a[i] = (float)v;
    }
    __syncthreads();

    for (int i = t; i < 4096; i += 256) {
        int r = i >> 6, c = i & 63;
        double acc = 0.0;
        for (int k = 0; k < 64; ++k) acc += (double)sM[r * 64 + k] * (double)sM[k * 64 + c];
        sQ[i] = (float)acc;
    }
    for (int i = t; i < 1024; i += 256) {
        int r = i >> 5, c = i & 31;
        double acc = 0.0;
        for (int k = 0; k < 32; ++k) acc += (double)s32a[r * 32 + k] * (double)s32a[k * 32 + c];
        s32b[i] = (float)acc;
    }
    __syncthreads();

    for (int i = t; i < 4096; i += 256) {
        int r = i >> 6, c = i & 63;
        double acc = 0.0;
        for (int k = 0; k < 64; ++k) acc += (double)sQ[r * 64 + k] * (double)sM[k * 64 + c];
        sA[i] = (float)acc;
    }
    for (int i = t; i < 1024; i += 256) {
        int r = i >> 5, c = i & 31;
        double acc = 0.0;
        for (int k = 0; k < 32; ++k) acc += (double)s32b[r * 32 + k] * (double)s32a[k * 32 + c];
        s32c[i] = (float)acc;
    }
    __syncthreads();

    // C[h][k] = sum_{h1 < 26} B[h][h1] * A[h1][k],  B[h][h1] = M32^3[h1][h]
    for (int i = t; i < 2048; i += 256) {
        int h = i >> 6, k = i & 63;
        double acc = 0.0;
        for (int h1 = 0; h1 < 26; ++h1)
            acc += (double)s32c[h1 * 32 + h] * (double)sA[h1 * 64 + k];
        Cout[i] = (float)acc;
    }
}

// ---------------------------------------------------------------------------
// Kernel 2: out[bc,d,h,w] = (d<26 && w<26) ? sum_k C[h,k] * x[bc,d,k,w] : 0
// One wave per (bc, d) slice; block of 256 = 4 slices.
// Lane l: wq = l&7 (w-quad), hb = l>>3 (h base); computes h in {hb, hb+8, hb+16, hb+24}.
// x tile (64 k x 32 w, fp32 = 8 KB/slice) staged via global_load_lds width 16.
// C staged in LDS with stride 65 to break the stride-64 bank conflict.
// ---------------------------------------------------------------------------
__global__ __launch_bounds__(256) void spectral_pool_kernel(
    const float* __restrict__ x, const float* __restrict__ C,
    float* __restrict__ out) {
    __shared__ __align__(16) float sC[32 * 65];
    __shared__ __align__(16) float xs[4][64 * 32];

    const int t  = threadIdx.x;
    const int blk = blockIdx.x;
    const int bc = blk >> 3;   // 0..255  (b*32 + c)
    const int dg = blk & 7;    // d-group of 4
    const int s  = t >> 6;     // slice within block = wave id
    const int l  = t & 63;     // lane
    const int wq = l & 7;      // w-quad
    const int hb = l >> 3;     // h base 0..7
    const int d  = dg * 4 + s;

    // stage C (all 256 threads)
    for (int i = t; i < 2048; i += 256) sC[(i >> 6) * 65 + (i & 63)] = C[i];

    const bool active = (d < 26);
    if (active) {
        const float* xp = x + (size_t)(bc * 64 + d) * 4096;
#pragma unroll
        for (int it = 0; it < 8; ++it) {
            int idx = it * 64 + l;          // float4 index within 64x32 tile
            int row = idx >> 3, q = idx & 7;
            const float* g = xp + row * 64 + q * 4;
            __builtin_amdgcn_global_load_lds(
                (const __attribute__((address_space(1))) void*)g,
                (__attribute__((address_space(3))) void*)(&xs[s][it * 256]),
                16, 0, 0);
        }
    }
    __syncthreads();

    float* op = out + (size_t)(bc * 32 + d) * 1024;

    if (!active) {
        const float4 z = make_float4(0.f, 0.f, 0.f, 0.f);
#pragma unroll
        for (int j = 0; j < 4; ++j)
            *(float4*)(op + (j * 64 + l) * 4) = z;
        return;
    }

    const float* xss = xs[s];
    const float* c0p = sC + hb * 65;
    const float* c1p = c0p + 8 * 65;
    const float* c2p = c0p + 16 * 65;
    const float* c3p = c0p + 24 * 65;

    float4 a0 = make_float4(0.f, 0.f, 0.f, 0.f);
    float4 a1 = a0, a2 = a0, a3 = a0;

#pragma unroll 16
    for (int k = 0; k < 64; ++k) {
        const float4 xv = *(const float4*)(xss + k * 32 + wq * 4);
        const float c0 = c0p[k], c1 = c1p[k], c2 = c2p[k], c3 = c3p[k];
        a0.x = fmaf(c0, xv.x, a0.x); a0.y = fmaf(c0, xv.y, a0.y);
        a0.z = fmaf(c0, xv.z, a0.z); a0.w = fmaf(c0, xv.w, a0.w);
        a1.x = fmaf(c1, xv.x, a1.x); a1.y = fmaf(c1, xv.y, a1.y);
        a1.z = fmaf(c1, xv.z, a1.z); a1.w = fmaf(c1, xv.w, a1.w);
        a2.x = fmaf(c2, xv.x, a2.x); a2.y = fmaf(c2, xv.y, a2.y);
        a2.z = fmaf(c2, xv.z, a2.z); a2.w = fmaf(c2, xv.w, a2.w);
        a3.x = fmaf(c3, xv.x, a3.x); a3.y = fmaf(c3, xv.y, a3.y);
        a3.z = fmaf(c3, xv.z, a3.z); a3.w = fmaf(c3, xv.w, a3.w);
    }

    // mask w >= 26 (only wq==6 partial: w=26,27 -> .z,.w; wq==7 fully zero)
    const int w0 = wq * 4;
    if (w0 >= 26) {
        a0 = a1 = a2 = a3 = make_float4(0.f, 0.f, 0.f, 0.f);
    } else if (w0 == 24) {
        a0.z = a0.w = 0.f; a1.z = a1.w = 0.f;
        a2.z = a2.w = 0.f; a3.z = a3.w = 0.f;
    }

    *(float4*)(op + hb * 32 + w0)        = a0;
    *(float4*)(op + (hb + 8) * 32 + w0)  = a1;
    *(float4*)(op + (hb + 16) * 32 + w0) = a2;
    *(float4*)(op + (hb + 24) * 32 + w0) = a3;
}

extern "C" void kernel_launch(void* const* d_in, const int* in_sizes, int n_in,
                              void* d_out, int out_size, void* d_ws, size_t ws_size,
                              hipStream_t stream) {
    const float* x = (const float*)d_in[0];
    float* out = (float*)d_out;
    float* C = (float*)d_ws;  // 32*64 fp32 = 8 KB scratch

    hipLaunchKernelGGL(build_C_kernel, dim3(1), dim3(256), 0, stream, C);
    hipLaunchKernelGGL(spectral_pool_kernel, dim3(2048), dim3(256), 0, stream,
                       x, C, out);
}

// Round 2
// 336.582 us; speedup vs baseline: 1.0156x; 1.0156x over previous
//
#include <hip/hip_runtime.h>

#define PI_F 3.14159265358979323846f

// ---------------------------------------------------------------------------
// Kernel 1: build the 32x64 combined operator C = B[:, :26] @ A[:26, :]
//   A = M64^3, B = (M32^T)^3 (the reference's matmul chain hits only the H
//   axis three times each way).
// All fp32: cos arguments are range-reduced EXACTLY in integer arithmetic
//   (cos(pi*m/128) has period m->m+256; cos(pi*m/64) period 128), so cosf
//   sees args in [0, 2pi) and C carries only ~1e-6 error.
// Single block, 256 threads, ~2.5 us.
// ---------------------------------------------------------------------------
__global__ __launch_bounds__(256) void build_C_kernel(float* __restrict__ Cout) {
    __shared__ float sM[64 * 64];    // M64
    __shared__ float sQ[64 * 64];    // M64^2
    __shared__ float sA[64 * 64];    // M64^3
    __shared__ float s32a[32 * 32];  // M32
    __shared__ float s32b[32 * 32];  // M32^2
    __shared__ float s32c[32 * 32];  // M32^3
    const int t = threadIdx.x;

    for (int i = t; i < 4096; i += 256) {
        int k = i >> 6, n = i & 63;
        int m = ((2 * n + 1) * k) & 255;               // exact mod-2pi reduction
        float v = (k == 0) ? 0.125f                     // 1/sqrt(64)
                           : 0.17677669529663688f       // sqrt(2/64)
                             * cosf(PI_F * (float)m / 128.0f);
        sM[i] = v;
    }
    for (int i = t; i < 1024; i += 256) {
        int k = i >> 5, n = i & 31;
        int m = ((2 * n + 1) * k) & 127;
        float v = (k == 0) ? 0.17677669529663688f       // 1/sqrt(32)
                           : 0.25f                      // sqrt(2/32)
                             * cosf(PI_F * (float)m / 64.0f);
        s32a[i] = v;
    }
    __syncthreads();

    for (int i = t; i < 4096; i += 256) {
        int r = i >> 6, c = i & 63;
        float acc = 0.f;
        for (int k = 0; k < 64; ++k) acc = fmaf(sM[r * 64 + k], sM[k * 64 + c], acc);
        sQ[i] = acc;
    }
    for (int i = t; i < 1024; i += 256) {
        int r = i >> 5, c = i & 31;
        float acc = 0.f;
        for (int k = 0; k < 32; ++k) acc = fmaf(s32a[r * 32 + k], s32a[k * 32 + c], acc);
        s32b[i] = acc;
    }
    __syncthreads();

    for (int i = t; i < 4096; i += 256) {
        int r = i >> 6, c = i & 63;
        float acc = 0.f;
        for (int k = 0; k < 64; ++k) acc = fmaf(sQ[r * 64 + k], sM[k * 64 + c], acc);
        sA[i] = acc;
    }
    for (int i = t; i < 1024; i += 256) {
        int r = i >> 5, c = i & 31;
        float acc = 0.f;
        for (int k = 0; k < 32; ++k) acc = fmaf(s32b[r * 32 + k], s32a[k * 32 + c], acc);
        s32c[i] = acc;
    }
    __syncthreads();

    // C[h][k] = sum_{h1<26} M32^3[h1][h] * A[h1][k]
    for (int i = t; i < 2048; i += 256) {
        int h = i >> 6, k = i & 63;
        float acc = 0.f;
        for (int h1 = 0; h1 < 26; ++h1)
            acc = fmaf(s32c[h1 * 32 + h], sA[h1 * 64 + k], acc);
        Cout[i] = acc;
    }
}

// ---------------------------------------------------------------------------
// Kernel 2: out[bc,d,h,w] = (d<26 && w<26) ? sum_k C[h,k] * x[bc,d,k,w] : 0
// One wave per (bc,d) slice; block = 4 slices. Lane l: wq=l&7, hb=l>>3,
// h in {hb, hb+8, hb+16, hb+24}. x tile staged via global_load_lds width 16.
// sC stride 68: 272 B rows keep 16 B alignment for float4-over-k reads
// (ds_read_b128) and the 8 hb-groups' reads tile all 32 banks (68%32 == 4).
// Inner loop: 8 ds_read_b128 + 64 fma per 4 k's  (was 20 LDS instrs).
// ---------------------------------------------------------------------------
#define FMA4(a, c, xv)                    \
    a.x = fmaf(c, xv.x, a.x);             \
    a.y = fmaf(c, xv.y, a.y);             \
    a.z = fmaf(c, xv.z, a.z);             \
    a.w = fmaf(c, xv.w, a.w)

__global__ __launch_bounds__(256) void spectral_pool_kernel(
    const float* __restrict__ x, const float* __restrict__ C,
    float* __restrict__ out) {
    __shared__ __align__(16) float sC[32 * 68];
    __shared__ __align__(16) float xs[4][64 * 32];

    const int t   = threadIdx.x;
    const int blk = blockIdx.x;
    const int bc  = blk >> 3;   // 0..255 (b*32 + c)
    const int dg  = blk & 7;    // d-group of 4
    const int s   = t >> 6;     // wave id = slice
    const int l   = t & 63;
    const int wq  = l & 7;      // w-quad
    const int hb  = l >> 3;     // h base 0..7
    const int d   = dg * 4 + s;

    for (int i = t; i < 2048; i += 256) sC[(i >> 6) * 68 + (i & 63)] = C[i];

    const bool active = (d < 26);
    if (active) {
        const float* xp = x + (size_t)(bc * 64 + d) * 4096;
#pragma unroll
        for (int it = 0; it < 8; ++it) {
            int idx = it * 64 + l;            // float4 index in 64x32 tile
            int row = idx >> 3, q = idx & 7;  // row<64, first 8 quads of W=64
            const float* g = xp + row * 64 + q * 4;
            __builtin_amdgcn_global_load_lds(
                (const __attribute__((address_space(1))) void*)g,
                (__attribute__((address_space(3))) void*)(&xs[s][it * 256]),
                16, 0, 0);
        }
    }
    __syncthreads();

    float* op = out + (size_t)(bc * 32 + d) * 1024;

    if (!active) {
        const float4 z = make_float4(0.f, 0.f, 0.f, 0.f);
#pragma unroll
        for (int j = 0; j < 4; ++j)
            *(float4*)(op + (j * 64 + l) * 4) = z;
        return;
    }

    const float* xss = xs[s] + wq * 4;
    const float* cp  = sC + hb * 68;

    float4 a0 = make_float4(0.f, 0.f, 0.f, 0.f);
    float4 a1 = a0, a2 = a0, a3 = a0;

#pragma unroll 4
    for (int k4 = 0; k4 < 64; k4 += 4) {
        const float4 c0 = *(const float4*)(cp + k4);
        const float4 c1 = *(const float4*)(cp + 8 * 68 + k4);
        const float4 c2 = *(const float4*)(cp + 16 * 68 + k4);
        const float4 c3 = *(const float4*)(cp + 24 * 68 + k4);
        const float4 x0 = *(const float4*)(xss + (k4 + 0) * 32);
        const float4 x1 = *(const float4*)(xss + (k4 + 1) * 32);
        const float4 x2 = *(const float4*)(xss + (k4 + 2) * 32);
        const float4 x3 = *(const float4*)(xss + (k4 + 3) * 32);

        FMA4(a0, c0.x, x0); FMA4(a0, c0.y, x1); FMA4(a0, c0.z, x2); FMA4(a0, c0.w, x3);
        FMA4(a1, c1.x, x0); FMA4(a1, c1.y, x1); FMA4(a1, c1.z, x2); FMA4(a1, c1.w, x3);
        FMA4(a2, c2.x, x0); FMA4(a2, c2.y, x1); FMA4(a2, c2.z, x2); FMA4(a2, c2.w, x3);
        FMA4(a3, c3.x, x0); FMA4(a3, c3.y, x1); FMA4(a3, c3.z, x2); FMA4(a3, c3.w, x3);
    }

    // mask w >= 26 (wq==6: zero .z/.w for w=26,27; wq==7 fully zero)
    const int w0 = wq * 4;
    if (w0 >= 26) {
        a0 = a1 = a2 = a3 = make_float4(0.f, 0.f, 0.f, 0.f);
    } else if (w0 == 24) {
        a0.z = a0.w = 0.f; a1.z = a1.w = 0.f;
        a2.z = a2.w = 0.f; a3.z = a3.w = 0.f;
    }

    *(float4*)(op + hb * 32 + w0)        = a0;
    *(float4*)(op + (hb + 8) * 32 + w0)  = a1;
    *(float4*)(op + (hb + 16) * 32 + w0) = a2;
    *(float4*)(op + (hb + 24) * 32 + w0) = a3;
}

extern "C" void kernel_launch(void* const* d_in, const int* in_sizes, int n_in,
                              void* d_out, int out_size, void* d_ws, size_t ws_size,
                              hipStream_t stream) {
    const float* x = (const float*)d_in[0];
    float* out = (float*)d_out;
    float* C = (float*)d_ws;  // 32*64 fp32 = 8 KB scratch

    hipLaunchKernelGGL(build_C_kernel, dim3(1), dim3(256), 0, stream, C);
    hipLaunchKernelGGL(spectral_pool_kernel, dim3(2048), dim3(256), 0, stream,
                       x, C, out);
}